// Round 2
// baseline (198.384 us; speedup 1.0000x reference)
//
#include <hip/hip_runtime.h>

// Multiresolution hash encoding (Instant-NGP style), MI355X.
// B=262144 samples, D=3, L=16 levels, T=2^19 rows/level, F=2 feats.
// Thread = one sample; full unroll over levels (lockstep level phases for L2
// locality); 8 uint32-hashed float2 gathers per level; row kept in registers
// and stored as 8 coalesced nontemporal 16B stores.

constexpr int      kT    = 524288;       // 2^19 rows per level
constexpr unsigned kMask = kT - 1;       // mod T == & mask
constexpr int      kB    = 262144;       // batch
constexpr unsigned kP1   = 2654435761u;  // prime for dim 1
constexpr unsigned kP2   = 805459861u;   // prime for dim 2 (dim 0 prime = 1)

typedef float f32x4 __attribute__((ext_vector_type(4)));  // native vec for nontemporal store

__global__ __launch_bounds__(256, 4) void hashenc(const float* __restrict__ x,
                                                  const float2* __restrict__ tables,
                                                  f32x4* __restrict__ out) {
    const int b = blockIdx.x * 256 + threadIdx.x;
    const float x0 = x[3 * b + 0];
    const float x1 = x[3 * b + 1];
    const float x2 = x[3 * b + 2];

    f32x4 o[8];  // 32 f32 output row, all indices compile-time (no scratch)

    // floor(16 * b^l), b = exp((ln512-ln16)/15): traced fp64 rounding chain;
    // ambiguous 2^k levels resolve UP -> {32,64,128,256,512}.
    // (If absmax ~1e-4: flip to 31/63/127/255/511.)
    constexpr int kRes[16] = {16, 20, 25, 32, 40, 50, 64, 80,
                              101, 128, 161, 203, 256, 322, 406, 512};

#pragma unroll
    for (int l = 0; l < 16; ++l) {
        const float res = (float)kRes[l];
        const float s0 = x0 * res, s1 = x1 * res, s2 = x2 * res;
        const float f0 = floorf(s0), f1 = floorf(s1), f2 = floorf(s2);
        const float r0 = s0 - f0, r1 = s1 - f1, r2 = s2 - f2;
        const unsigned c0 = (unsigned)f0;
        const unsigned c1 = (unsigned)f1;
        const unsigned c2 = (unsigned)f2;
        // hash components; only low 19 bits matter -> uint32 math is exact
        const unsigned h1a = c1 * kP1, h1b = h1a + kP1;
        const unsigned h2a = c2 * kP2, h2b = h2a + kP2;
        const float2* __restrict__ tab = tables + (size_t)l * kT;
        const float w0a = 1.0f - r0, w1a = 1.0f - r1, w2a = 1.0f - r2;
        float a0 = 0.0f, a1 = 0.0f;
#pragma unroll
        for (int v = 0; v < 8; ++v) {
            const unsigned g0 = (v & 1) ? (c0 + 1u) : c0;
            const unsigned g1 = (v & 2) ? h1b : h1a;
            const unsigned g2 = (v & 4) ? h2b : h2a;
            const unsigned idx = (g0 ^ g1 ^ g2) & kMask;
            const float2 f = tab[idx];
            const float w = ((v & 1) ? r0 : w0a) *
                            ((v & 2) ? r1 : w1a) *
                            ((v & 4) ? r2 : w2a);
            a0 = fmaf(w, f.x, a0);
            a1 = fmaf(w, f.y, a1);
        }
        if (l & 1) { o[l >> 1].z = a0; o[l >> 1].w = a1; }
        else       { o[l >> 1].x = a0; o[l >> 1].y = a1; }
    }

    f32x4* op = out + (size_t)b * 8;
#pragma unroll
    for (int k = 0; k < 8; ++k) __builtin_nontemporal_store(o[k], op + k);
}

extern "C" void kernel_launch(void* const* d_in, const int* in_sizes, int n_in,
                              void* d_out, int out_size, void* d_ws, size_t ws_size,
                              hipStream_t stream) {
    const float*  x      = (const float*)d_in[0];
    const float2* tables = (const float2*)d_in[1];
    f32x4*        out    = (f32x4*)d_out;
    hashenc<<<kB / 256, 256, 0, stream>>>(x, tables, out);
}